// Round 3
// baseline (452.652 us; speedup 1.0000x reference)
//
#include <hip/hip_runtime.h>
#include <math.h>

#define TPB 256
#define TPB_P 512
#define LRATE 0.005f

// Bucketed partition parameters
#define LOG_NPB 10
#define NPB (1 << LOG_NPB)   // 1024 nodes per partition bucket
#define CAP 14336            // mean ~10225 edges/bucket (E=5M, 489 buckets); +40 sigma
#define CHUNK 4096           // edges per partition block
#define CPT (CHUNK / TPB_P)  // 8 edges per thread

// k_agg sub-buckets: 4 per bucket, 256 nodes each -> 16KB accumulator
#define LOG_SUB 8
#define NSUB 256
#define NBIN 256             // sort bins: (dl>>8)<<6 | src_tile

// src-tile: tile = src >> 13 (8192 nodes -> 128KB of hp); NTILE=64 covers src<2^19
#define NTILE 64

// fixed-point accumulator scale (LDS int atomics are native ds_add_u32;
// float LDS atomicAdd compiles to a CAS loop -- the round-1 regression)
#define FXS  65536.0f
#define FXSI (1.0f / 65536.0f)

// ---------------------------------------------------------------------------
// fp8 e4m3fn helpers (OCP).
#if __has_builtin(__builtin_amdgcn_cvt_f32_fp8) && __has_builtin(__builtin_amdgcn_cvt_pk_fp8_f32)
__device__ __forceinline__ float fp8_dec(unsigned char v) {
    return __builtin_amdgcn_cvt_f32_fp8((int)v, 0);
}
__device__ __forceinline__ unsigned fp8_pk4(float a, float b, float c, float d) {
    int w = __builtin_amdgcn_cvt_pk_fp8_f32(a, b, 0, false);
    w = __builtin_amdgcn_cvt_pk_fp8_f32(c, d, w, true);
    return (unsigned)w;
}
#else
__device__ __forceinline__ unsigned char fp8_enc1(float f) {
    unsigned u = __float_as_uint(f);
    unsigned s = (u >> 24) & 0x80u;
    u &= 0x7FFFFFFFu;
    if (u >= 0x43E00000u) return (unsigned char)(s | 0x7E);
    if (u < 0x3C800000u) {
        float a = __uint_as_float(u);
        int m = (int)rintf(a * 512.f);
        return (unsigned char)(s | (unsigned)m);
    }
    unsigned mant = u & 0x7FFFFFu;
    unsigned rest = mant & 0xFFFFFu;
    unsigned keep = u >> 20;
    keep += (rest > 0x80000u || (rest == 0x80000u && (keep & 1u))) ? 1u : 0u;
    int eb = (int)(keep >> 3) - 127 + 7;
    return (unsigned char)(s | (unsigned)((eb << 3) | (int)(keep & 7u)));
}
__device__ __forceinline__ float fp8_dec(unsigned char v) {
    unsigned s = ((unsigned)(v & 0x80u)) << 24;
    unsigned e = (v >> 3) & 0xFu;
    unsigned m = v & 7u;
    if (e == 0) {
        float r = (float)m * 0.001953125f;
        return (v & 0x80u) ? -r : r;
    }
    return __uint_as_float(s | ((e + 120u) << 23) | (m << 20));
}
__device__ __forceinline__ unsigned fp8_pk4(float a, float b, float c, float d) {
    return (unsigned)fp8_enc1(a) | ((unsigned)fp8_enc1(b) << 8) |
           ((unsigned)fp8_enc1(c) << 16) | ((unsigned)fp8_enc1(d) << 24);
}
#endif

#if __has_builtin(__builtin_amdgcn_cvt_pk_f32_fp8)
typedef float __attribute__((ext_vector_type(2))) f32x2;
__device__ __forceinline__ void fp8_dec4(unsigned w, float& a, float& b, float& c, float& d) {
    f32x2 lo = __builtin_amdgcn_cvt_pk_f32_fp8((int)w, false);
    f32x2 hi = __builtin_amdgcn_cvt_pk_f32_fp8((int)w, true);
    a = lo[0]; b = lo[1]; c = hi[0]; d = hi[1];
}
#else
__device__ __forceinline__ void fp8_dec4(unsigned w, float& a, float& b, float& c, float& d) {
    a = fp8_dec((unsigned char)(w & 0xFFu));
    b = fp8_dec((unsigned char)((w >> 8) & 0xFFu));
    c = fp8_dec((unsigned char)((w >> 16) & 0xFFu));
    d = fp8_dec((unsigned char)((w >> 24) & 0xFFu));
}
#endif

// ---------------------------------------------------------------------------
// K_PART: partition edges into per-bucket record arrays (bucket = dst >> 10).
// Record = (src << 10) | (dst & 1023).
__global__ __launch_bounds__(TPB_P) void k_partition(const int* __restrict__ src,
                                                     const int* __restrict__ dst,
                                                     int* __restrict__ bcur,   // [nbuck*16] padded, zeroed
                                                     int* __restrict__ grec,   // [nbuck*CAP]
                                                     int E, int nbuck) {
    __shared__ int hist[TPB_P];
    __shared__ int sc[TPB_P];
    __shared__ int lstart[TPB_P];
    __shared__ int lcur[TPB_P];
    __shared__ int gbase[TPB_P];
    __shared__ int lbuf[CHUNK];
    __shared__ unsigned short bbuf[CHUNK];

    int t = threadIdx.x;
    int chunkBase = blockIdx.x * CHUNK;
    hist[t] = 0;
    __syncthreads();

    int myb[CPT], myrec[CPT];
#pragma unroll
    for (int k = 0; k < CPT; k++) {
        int e = chunkBase + k * TPB_P + t;
        if (e < E) {
            int d = dst[e];
            int s = src[e];
            int b = d >> LOG_NPB;
            myb[k] = b;
            myrec[k] = (s << LOG_NPB) | (d & (NPB - 1));
            atomicAdd(&hist[b], 1);
        } else myb[k] = -1;
    }
    __syncthreads();

    int c = hist[t];
    sc[t] = c;
    __syncthreads();
#pragma unroll
    for (int off = 1; off < TPB_P; off <<= 1) {
        int add = (t >= off) ? sc[t - off] : 0;
        __syncthreads();
        sc[t] += add;
        __syncthreads();
    }
    int excl = sc[t] - c;
    lstart[t] = excl;
    lcur[t] = excl;
    if (t < nbuck && c > 0) gbase[t] = atomicAdd(&bcur[t * 16], c);
    __syncthreads();

#pragma unroll
    for (int k = 0; k < CPT; k++) {
        if (myb[k] >= 0) {
            int p = atomicAdd(&lcur[myb[k]], 1);
            lbuf[p] = myrec[k];
            bbuf[p] = (unsigned short)myb[k];
        }
    }
    __syncthreads();

    int total = E - chunkBase; if (total > CHUNK) total = CHUNK;
    for (int p = t; p < total; p += TPB_P) {
        int b = (int)bbuf[p];
        int pos = gbase[b] + (p - lstart[b]);
        if (pos < CAP) grec[(size_t)b * CAP + pos] = lbuf[p];
    }
}

// K_SORT: per-bucket counting sort by bin = ((dl>>8)<<6 | src_tile).
// - orders records into 4 contiguous 256-node sub-buckets (k_agg runs 4
//   blocks/bucket with 16KB accumulators -> occupancy 2->~5 blocks/CU)
// - within a sub-bucket, records are src-tile ordered -> all co-resident
//   k_agg blocks sweep hp in phase (L2-resident window)
// - also computes deg/dinv (folds the old k_deg dispatch in)
// Sub-bucket starts stored at bcur[b*16 + 8 + h].
__global__ __launch_bounds__(TPB) void k_sort(int* __restrict__ bcur,
                                              int* __restrict__ grec,
                                              float* __restrict__ dinv, int N) {
    __shared__ int lbuf[CAP];     // 57344 B
    __shared__ int obuf[CAP];     // 57344 B
    __shared__ int deg[NPB];      // 4096 B
    __shared__ int hist[NBIN];
    __shared__ int curp[NBIN];
    __shared__ int sc[NBIN];
    int t = threadIdx.x;
    int b = blockIdx.x;
    int cnt = bcur[b * 16]; if (cnt > CAP) cnt = CAP;
    const size_t base = (size_t)b * CAP;

    for (int i = t; i < NBIN; i += TPB) hist[i] = 0;
    for (int i = t; i < NPB; i += TPB) deg[i] = 0;
    __syncthreads();
    for (int i = t; i < cnt; i += TPB) {
        int r = grec[base + i];
        lbuf[i] = r;
        int dl = r & (NPB - 1);
        atomicAdd(&deg[dl], 1);
        int bin = ((dl >> LOG_SUB) << 6) | (int)(((unsigned)r) >> 23);
        atomicAdd(&hist[bin], 1);
    }
    __syncthreads();
    if (t < NBIN) sc[t] = hist[t];
    __syncthreads();
    for (int off = 1; off < NBIN; off <<= 1) {
        int v = (t < NBIN && t >= off) ? sc[t - off] : 0;
        __syncthreads();
        if (t < NBIN) sc[t] += v;
        __syncthreads();
    }
    if (t < NBIN) curp[t] = sc[t] - hist[t];   // exclusive prefix
    __syncthreads();
    if (t < 4) bcur[b * 16 + 8 + t] = curp[t * 64];   // sub-bucket starts
    __syncthreads();
    for (int i = t; i < cnt; i += TPB) {
        int r = lbuf[i];
        int dl = r & (NPB - 1);
        int bin = ((dl >> LOG_SUB) << 6) | (int)(((unsigned)r) >> 23);
        int p = atomicAdd(&curp[bin], 1);
        obuf[p] = r;
    }
    __syncthreads();
    for (int i = t; i < cnt; i += TPB) grec[base + i] = obuf[i];
    int nodeBase = b << LOG_NPB;
    for (int i = t; i < NPB; i += TPB) {
        int node = nodeBase + i;
        if (node < N) dinv[node] = rsqrtf((float)(deg[i] + 1));
    }
}

// ---------------------------------------------------------------------------
// K3: hp = fp8_e4m3( dinv * (x @ W.T) )
__global__ __launch_bounds__(TPB) void k_h(const float* __restrict__ xc,
                                           const float* __restrict__ W,
                                           const float* __restrict__ dinv,
                                           unsigned* __restrict__ hp, int n) {
    __shared__ float sW[256];
    if (threadIdx.x < 256) sW[threadIdx.x] = W[threadIdx.x];
    __syncthreads();
    int i = blockIdx.x * blockDim.x + threadIdx.x;
    int stride = gridDim.x * blockDim.x;
    for (; i < n; i += stride) {
        float x[16];
        const float4* xr = (const float4*)(xc + (size_t)i * 16);
#pragma unroll
        for (int q = 0; q < 4; q++) {
            float4 v = xr[q];
            x[4*q+0] = v.x; x[4*q+1] = v.y; x[4*q+2] = v.z; x[4*q+3] = v.w;
        }
        float di = dinv[i];
        float hv[16];
#pragma unroll
        for (int j = 0; j < 16; j++) {
            float s = 0.f;
#pragma unroll
            for (int k = 0; k < 16; k++) s = fmaf(x[k], sW[j*16 + k], s);
            hv[j] = di * s;
        }
        uint4 w;
        w.x = fp8_pk4(hv[0],  hv[1],  hv[2],  hv[3]);
        w.y = fp8_pk4(hv[4],  hv[5],  hv[6],  hv[7]);
        w.z = fp8_pk4(hv[8],  hv[9],  hv[10], hv[11]);
        w.w = fp8_pk4(hv[12], hv[13], hv[14], hv[15]);
        ((uint4*)hp)[i] = w;
    }
}

// ---------------------------------------------------------------------------
// K_AGG: edge-parallel aggregation + finalize. 4 blocks per bucket; block
// (bkt,h) owns 256 nodes and the contiguous record range [rs,re) produced
// by k_sort. Phase 1: 4 lanes/edge, fp8 decode, s16.16 ds_add_u32 into
// accI[j][dl8^j] (16KB -> ~5 blocks/CU occupancy). Phase 2: 16 lanes/row
// finalize z = relu(dinv*(acc+self)+b); dW/db reduced via LDS overlay.
__global__ __launch_bounds__(TPB) void k_agg(const int* __restrict__ bcur,
                                             const int* __restrict__ grec,
                                             const float* __restrict__ dinv,
                                             const unsigned* __restrict__ hp32,
                                             const float* __restrict__ b,
                                             const float* __restrict__ xc,
                                             float* __restrict__ z,
                                             float* __restrict__ partial,
                                             int nb, int N) {
    __shared__ int accI[256 * 17];   // first 16*256 = acc planes; 17408B total (red overlay)
    int t = threadIdx.x;
    int bkt = blockIdx.x >> 2;
    int h = blockIdx.x & 3;
    int cnt = bcur[bkt * 16]; if (cnt > CAP) cnt = CAP;
    int rs = bcur[bkt * 16 + 8 + h];
    int re = (h == 3) ? cnt : bcur[bkt * 16 + 9 + h];
    if (rs > cnt) rs = cnt;
    if (re > cnt) re = cnt;
    const int nodeBase = (bkt << LOG_NPB) + (h << LOG_SUB);
    const size_t recBase = (size_t)bkt * CAP;

    {
        int4 zv = make_int4(0, 0, 0, 0);
        int4* a4 = (int4*)accI;
        for (int i = t; i < 16 * NSUB / 4; i += TPB) a4[i] = zv;
    }
    __syncthreads();

    // ---- Phase 1: edge-parallel scatter (fixed-point int atomics) ----
    int q = t & 3;          // j-quad (j = 4q..4q+3)
    int gi = t >> 2;        // edge slot 0..63
    int j0 = q * 4;
    int base = rs;
    for (; base + 512 <= re; base += 512) {
        int rec[8];
#pragma unroll
        for (int u = 0; u < 8; u++) rec[u] = grec[recBase + base + u * 64 + gi];
        unsigned w[8];
#pragma unroll
        for (int u = 0; u < 8; u++)
            w[u] = hp32[(size_t)(((unsigned)rec[u]) >> LOG_NPB) * 4 + q];
#pragma unroll
        for (int u = 0; u < 8; u++) {
            int dl = rec[u] & (NSUB - 1);
            float f0, f1, f2, f3;
            fp8_dec4(w[u], f0, f1, f2, f3);
            atomicAdd(&accI[(j0 + 0) * NSUB + (dl ^ (j0 + 0))], (int)(f0 * FXS));
            atomicAdd(&accI[(j0 + 1) * NSUB + (dl ^ (j0 + 1))], (int)(f1 * FXS));
            atomicAdd(&accI[(j0 + 2) * NSUB + (dl ^ (j0 + 2))], (int)(f2 * FXS));
            atomicAdd(&accI[(j0 + 3) * NSUB + (dl ^ (j0 + 3))], (int)(f3 * FXS));
        }
    }
    for (int e = base + gi; e < re; e += 64) {
        int rec = grec[recBase + e];
        unsigned w = hp32[(size_t)(((unsigned)rec) >> LOG_NPB) * 4 + q];
        int dl = rec & (NSUB - 1);
        float f0, f1, f2, f3;
        fp8_dec4(w, f0, f1, f2, f3);
        atomicAdd(&accI[(j0 + 0) * NSUB + (dl ^ (j0 + 0))], (int)(f0 * FXS));
        atomicAdd(&accI[(j0 + 1) * NSUB + (dl ^ (j0 + 1))], (int)(f1 * FXS));
        atomicAdd(&accI[(j0 + 2) * NSUB + (dl ^ (j0 + 2))], (int)(f2 * FXS));
        atomicAdd(&accI[(j0 + 3) * NSUB + (dl ^ (j0 + 3))], (int)(f3 * FXS));
    }
    __syncthreads();

    // ---- Phase 2: finalize rows (16 lanes per row, 16 iterations) ----
    const unsigned char* hpB = (const unsigned char*)hp32;
    int j = t & 15;
    int g0 = t >> 4;        // 0..15 row groups
    float bj = b[j];
    float accW[16];
#pragma unroll
    for (int k = 0; k < 16; k++) accW[k] = 0.f;
    float accB = 0.f;

    for (int i = g0; i < NSUB; i += 16) {
        int node = nodeBase + i;
        if (node >= N) break;
        float sv = fp8_dec(hpB[(size_t)node * 16 + j]);           // self-loop
        float aj = fmaf((float)accI[j * NSUB + (i ^ j)], FXSI, sv);
        float zj = fmaxf(fmaf(dinv[node], aj, bj), 0.f);
        z[(size_t)node * 16 + j] = zj;
        float wdj = 4.f * zj * zj;
        accB += wdj;
        const float4* xrow = (const float4*)(xc + (size_t)node * 16);
        float4 x0 = xrow[0], x1 = xrow[1], x2 = xrow[2], x3 = xrow[3];
        accW[0]  = fmaf(x0.x, wdj, accW[0]);  accW[1]  = fmaf(x0.y, wdj, accW[1]);
        accW[2]  = fmaf(x0.z, wdj, accW[2]);  accW[3]  = fmaf(x0.w, wdj, accW[3]);
        accW[4]  = fmaf(x1.x, wdj, accW[4]);  accW[5]  = fmaf(x1.y, wdj, accW[5]);
        accW[6]  = fmaf(x1.z, wdj, accW[6]);  accW[7]  = fmaf(x1.w, wdj, accW[7]);
        accW[8]  = fmaf(x2.x, wdj, accW[8]);  accW[9]  = fmaf(x2.y, wdj, accW[9]);
        accW[10] = fmaf(x2.z, wdj, accW[10]); accW[11] = fmaf(x2.w, wdj, accW[11]);
        accW[12] = fmaf(x3.x, wdj, accW[12]); accW[13] = fmaf(x3.y, wdj, accW[13]);
        accW[14] = fmaf(x3.z, wdj, accW[14]); accW[15] = fmaf(x3.w, wdj, accW[15]);
    }
    __syncthreads();   // all accI reads done -> safe to alias red onto accI

    float (*red)[17] = (float (*)[17])accI;   // 256*17*4 = 17408 B == sizeof(accI)
#pragma unroll
    for (int k = 0; k < 16; k++) red[t][k] = accW[k];
    red[t][16] = accB;
    __syncthreads();
    int kk = t >> 4;
    int jj = t & 15;
    float s = 0.f;
#pragma unroll
    for (int g = 0; g < 16; g++) s += red[g * 16 + jj][kk];
    partial[(size_t)(kk * 16 + jj) * nb + blockIdx.x] = s;
    if (t < 16) {
        float sb = 0.f;
#pragma unroll
        for (int g = 0; g < 16; g++) sb += red[g * 16 + t][16];
        partial[(size_t)(256 + t) * nb + blockIdx.x] = sb;
    }
}

// K5b: one 64-lane wave per (layer,elem): coalesced sum over nb partials.
__global__ __launch_bounds__(TPB) void k_reduce(const float* __restrict__ partial,
                                                float* __restrict__ acc,
                                                int nb, int total) {
    int wid = (blockIdx.x * blockDim.x + threadIdx.x) >> 6;
    int lane = threadIdx.x & 63;
    if (wid >= total) return;
    const float* p = partial + (size_t)wid * nb;
    float s = 0.f;
    for (int b = lane; b < nb; b += 64) s += p[b];
#pragma unroll
    for (int off = 32; off > 0; off >>= 1) s += __shfl_down(s, off, 64);
    if (lane == 0) acc[wid] = s;
}

// ---------------------------------------------------------------------------
__device__ __forceinline__ float local_loss_f(float g, int positive) {
    const float t = 0.0f;
    if (positive) {
        if (g > t + 10.f) return 0.f;
        if (g < t - 10.f) return t - g;
        return log1pf(expf(t - g));
    } else {
        if (g > t + 10.f) return t + g;
        if (g < t - 10.f) return 0.f;
        return log1pf(expf(g + t));
    }
}

__global__ void k_final(const float* __restrict__ W1, const float* __restrict__ b1,
                        const float* __restrict__ acc, const int* __restrict__ positive,
                        float* __restrict__ outv) {
    int t = threadIdx.x;
    if (t < 256) {
        int jj = t >> 4, kk = t & 15;   // Wc[jj][kk] -= LR * dW[kk][jj]
        float s = 0.f;
#pragma unroll
        for (int l = 0; l < 3; l++) s += acc[l * 272 + kk * 16 + jj];
        outv[1 + t] = W1[t] - LRATE * s;
    }
    if (t < 16) {
        float s = 0.f;
#pragma unroll
        for (int l = 0; l < 3; l++) s += acc[l * 272 + 256 + t];
        outv[257 + t] = b1[t] - LRATE * s;
    }
    if (t == 0) {
        int pos = positive[0];
        float agg = 0.f;
#pragma unroll
        for (int l = 0; l < 3; l++) {
            float g = 0.f;
#pragma unroll
            for (int jj = 0; jj < 16; jj++) g += acc[l * 272 + 256 + jj];
            g *= (1.0f / 64.0f);
            agg += local_loss_f(g, pos);
        }
        outv[0] = agg;
    }
}

extern "C" void kernel_launch(void* const* d_in, const int* in_sizes, int n_in,
                              void* d_out, int out_size, void* d_ws, size_t ws_size,
                              hipStream_t stream) {
    const float* x  = (const float*)d_in[0];
    const int*   ei = (const int*)d_in[1];
    const float* W1 = (const float*)d_in[2];
    const float* b1 = (const float*)d_in[3];
    const float* W2 = (const float*)d_in[4];
    const float* b2 = (const float*)d_in[5];
    const float* W3 = (const float*)d_in[6];
    const float* b3 = (const float*)d_in[7];
    const int* positive = (const int*)d_in[8];
    float* outv = (float*)d_out;

    const int N = in_sizes[0] / 16;
    const int E = in_sizes[1] / 2;
    const int nbuck = (N + NPB - 1) >> LOG_NPB;     // 489 for N=500k
    const int nagg = nbuck * 4;                     // k_agg blocks / partials

    // Workspace carve-out (256B aligned).
    char* ws = (char*)d_ws;
    size_t off = 0;
    auto carve = [&](size_t bytes) -> void* {
        void* p = ws + off;
        off = (off + bytes + 255) & ~(size_t)255;
        return p;
    };
    int*   bcur   = (int*)  carve((size_t)nbuck * 16 * 4);     // counts + sub-starts
    int*   grec   = (int*)  carve((size_t)nbuck * CAP * 4);    // 28 MB, lives all layers
    float* dinv   = (float*)carve((size_t)N * 4);
    float* acc    = (float*)carve(3 * 272 * 4);
    float* part   = (float*)carve((size_t)3 * 272 * nagg * 4);
    unsigned* hp  = (unsigned*)carve((size_t)N * 16);          // fp8 rows, 8 MB
    float* P1     = (float*)carve((size_t)N * 64);
    float* P2     = (float*)carve((size_t)N * 64);

    hipMemsetAsync(bcur, 0, (size_t)nbuck * 16 * 4, stream);

    const int* src = ei;
    const int* dst = ei + E;

    // --- Bucketed edge partition + sub-bucket/tile sort (once, reused 3x) ---
    int partBlocks = (E + CHUNK - 1) / CHUNK;
    k_partition<<<partBlocks, TPB_P, 0, stream>>>(src, dst, bcur, grec, E, nbuck);
    k_sort<<<nbuck, TPB, 0, stream>>>(bcur, grec, dinv, N);

    // --- 3 layers ---
    const float* Ws[3] = {W1, W2, W3};
    const float* bss[3] = {b1, b2, b3};
    float* outs[3] = {P1, P2, P1};   // L1: x->P1; L2: P1->P2; L3: P2->P1

    int nodeBlocks = (N + TPB - 1) / TPB;

    const float* xc = x;
    for (int l = 0; l < 3; l++) {
        k_h<<<nodeBlocks, TPB, 0, stream>>>(xc, Ws[l], dinv, hp, N);
        k_agg<<<nagg, TPB, 0, stream>>>(bcur, grec, dinv, hp, bss[l],
                                        xc, outs[l],
                                        part + (size_t)l * 272 * nagg, nagg, N);
        xc = outs[l];
    }
    int totalElems = 3 * 272;
    k_reduce<<<(totalElems * 64 + TPB - 1) / TPB, TPB, 0, stream>>>(part, acc, nagg, totalElems);
    k_final<<<1, 256, 0, stream>>>(W1, b1, acc, positive, outv);
}

// Round 4
// 389.655 us; speedup vs baseline: 1.1617x; 1.1617x over previous
//
#include <hip/hip_runtime.h>
#include <math.h>

#define TPB 256
#define TPB_P 512
#define TPB_A 512            // k_agg block size: 64KB acc -> 2 blocks/CU, 16 waves/CU
#define LRATE 0.005f

// Bucketed partition parameters
#define LOG_NPB 10
#define NPB (1 << LOG_NPB)   // 1024 nodes per bucket
#define CAP 14336            // mean ~10225 edges/bucket (E=5M, 489 buckets); +40 sigma
#define CHUNK 4096           // edges per partition block
#define CPT (CHUNK / TPB_P)  // 8 edges per thread

// src-tile sort: tile = 8192 nodes -> 128KB of hp; 512-edge chunks span ~3
// tiles (0.4MB) -> all 489 co-resident blocks sweep in phase, L2-resident.
// (Round-3 lesson: 4x smaller blocks -> 13-tile windows -> drift -> 3x HBM.)
#define NTILE 64             // covers src < 2^19 (N=500k)

// fixed-point accumulator scale (LDS int atomics are native ds_add_u32;
// float LDS atomicAdd compiles to a CAS loop -- the round-1 regression)
#define FXS  65536.0f
#define FXSI (1.0f / 65536.0f)

// ---------------------------------------------------------------------------
// fp8 e4m3fn helpers (OCP).
#if __has_builtin(__builtin_amdgcn_cvt_f32_fp8) && __has_builtin(__builtin_amdgcn_cvt_pk_fp8_f32)
__device__ __forceinline__ float fp8_dec(unsigned char v) {
    return __builtin_amdgcn_cvt_f32_fp8((int)v, 0);
}
__device__ __forceinline__ unsigned fp8_pk4(float a, float b, float c, float d) {
    int w = __builtin_amdgcn_cvt_pk_fp8_f32(a, b, 0, false);
    w = __builtin_amdgcn_cvt_pk_fp8_f32(c, d, w, true);
    return (unsigned)w;
}
#else
__device__ __forceinline__ unsigned char fp8_enc1(float f) {
    unsigned u = __float_as_uint(f);
    unsigned s = (u >> 24) & 0x80u;
    u &= 0x7FFFFFFFu;
    if (u >= 0x43E00000u) return (unsigned char)(s | 0x7E);
    if (u < 0x3C800000u) {
        float a = __uint_as_float(u);
        int m = (int)rintf(a * 512.f);
        return (unsigned char)(s | (unsigned)m);
    }
    unsigned mant = u & 0x7FFFFFu;
    unsigned rest = mant & 0xFFFFFu;
    unsigned keep = u >> 20;
    keep += (rest > 0x80000u || (rest == 0x80000u && (keep & 1u))) ? 1u : 0u;
    int eb = (int)(keep >> 3) - 127 + 7;
    return (unsigned char)(s | (unsigned)((eb << 3) | (int)(keep & 7u)));
}
__device__ __forceinline__ float fp8_dec(unsigned char v) {
    unsigned s = ((unsigned)(v & 0x80u)) << 24;
    unsigned e = (v >> 3) & 0xFu;
    unsigned m = v & 7u;
    if (e == 0) {
        float r = (float)m * 0.001953125f;
        return (v & 0x80u) ? -r : r;
    }
    return __uint_as_float(s | ((e + 120u) << 23) | (m << 20));
}
__device__ __forceinline__ unsigned fp8_pk4(float a, float b, float c, float d) {
    return (unsigned)fp8_enc1(a) | ((unsigned)fp8_enc1(b) << 8) |
           ((unsigned)fp8_enc1(c) << 16) | ((unsigned)fp8_enc1(d) << 24);
}
#endif

#if __has_builtin(__builtin_amdgcn_cvt_pk_f32_fp8)
typedef float __attribute__((ext_vector_type(2))) f32x2;
__device__ __forceinline__ void fp8_dec4(unsigned w, float& a, float& b, float& c, float& d) {
    f32x2 lo = __builtin_amdgcn_cvt_pk_f32_fp8((int)w, false);
    f32x2 hi = __builtin_amdgcn_cvt_pk_f32_fp8((int)w, true);
    a = lo[0]; b = lo[1]; c = hi[0]; d = hi[1];
}
#else
__device__ __forceinline__ void fp8_dec4(unsigned w, float& a, float& b, float& c, float& d) {
    a = fp8_dec((unsigned char)(w & 0xFFu));
    b = fp8_dec((unsigned char)((w >> 8) & 0xFFu));
    c = fp8_dec((unsigned char)((w >> 16) & 0xFFu));
    d = fp8_dec((unsigned char)((w >> 24) & 0xFFu));
}
#endif

// ---------------------------------------------------------------------------
// K_PART: partition edges into per-bucket record arrays (bucket = dst >> 10).
// Record = (src << 10) | (dst & 1023).
__global__ __launch_bounds__(TPB_P) void k_partition(const int* __restrict__ src,
                                                     const int* __restrict__ dst,
                                                     int* __restrict__ bcur,   // [nbuck*16] padded, zeroed
                                                     int* __restrict__ grec,   // [nbuck*CAP]
                                                     int E, int nbuck) {
    __shared__ int hist[TPB_P];
    __shared__ int sc[TPB_P];
    __shared__ int lstart[TPB_P];
    __shared__ int lcur[TPB_P];
    __shared__ int gbase[TPB_P];
    __shared__ int lbuf[CHUNK];
    __shared__ unsigned short bbuf[CHUNK];

    int t = threadIdx.x;
    int chunkBase = blockIdx.x * CHUNK;
    hist[t] = 0;
    __syncthreads();

    int myb[CPT], myrec[CPT];
#pragma unroll
    for (int k = 0; k < CPT; k++) {
        int e = chunkBase + k * TPB_P + t;
        if (e < E) {
            int d = dst[e];
            int s = src[e];
            int b = d >> LOG_NPB;
            myb[k] = b;
            myrec[k] = (s << LOG_NPB) | (d & (NPB - 1));
            atomicAdd(&hist[b], 1);
        } else myb[k] = -1;
    }
    __syncthreads();

    int c = hist[t];
    sc[t] = c;
    __syncthreads();
#pragma unroll
    for (int off = 1; off < TPB_P; off <<= 1) {
        int add = (t >= off) ? sc[t - off] : 0;
        __syncthreads();
        sc[t] += add;
        __syncthreads();
    }
    int excl = sc[t] - c;
    lstart[t] = excl;
    lcur[t] = excl;
    if (t < nbuck && c > 0) gbase[t] = atomicAdd(&bcur[t * 16], c);
    __syncthreads();

#pragma unroll
    for (int k = 0; k < CPT; k++) {
        if (myb[k] >= 0) {
            int p = atomicAdd(&lcur[myb[k]], 1);
            lbuf[p] = myrec[k];
            bbuf[p] = (unsigned short)myb[k];
        }
    }
    __syncthreads();

    int total = E - chunkBase; if (total > CHUNK) total = CHUNK;
    for (int p = t; p < total; p += TPB_P) {
        int b = (int)bbuf[p];
        int pos = gbase[b] + (p - lstart[b]);
        if (pos < CAP) grec[(size_t)b * CAP + pos] = lbuf[p];
    }
}

// K_SORT: per-bucket counting sort by src-tile (rec >> 23 == src >> 13).
// All co-resident k_agg blocks sweep hp in the same tile order -> L2-resident
// gather window. Also computes deg/dinv (folds old k_deg in). Entirely in
// LDS (~117KB, 1 block/CU). Runs once, reused 3x.
__global__ __launch_bounds__(TPB) void k_sort(int* __restrict__ bcur,
                                              int* __restrict__ grec,
                                              float* __restrict__ dinv, int N) {
    __shared__ int lbuf[CAP];     // 57344 B
    __shared__ int obuf[CAP];     // 57344 B
    __shared__ int deg[NPB];      // 4096 B
    __shared__ int hist[NTILE];
    __shared__ int curp[NTILE];
    int t = threadIdx.x;
    int b = blockIdx.x;
    int cnt = bcur[b * 16]; if (cnt > CAP) cnt = CAP;
    const size_t base = (size_t)b * CAP;

    for (int i = t; i < NTILE; i += TPB) hist[i] = 0;
    for (int i = t; i < NPB; i += TPB) deg[i] = 0;
    __syncthreads();
    for (int i = t; i < cnt; i += TPB) {
        int r = grec[base + i];
        lbuf[i] = r;
        atomicAdd(&deg[r & (NPB - 1)], 1);
        atomicAdd(&hist[((unsigned)r) >> 23], 1);   // int LDS atomic: native
    }
    __syncthreads();
    if (t == 0) {
        int run = 0;
#pragma unroll
        for (int k = 0; k < NTILE; k++) { int c = hist[k]; curp[k] = run; run += c; }
    }
    __syncthreads();
    for (int i = t; i < cnt; i += TPB) {
        int r = lbuf[i];
        int p = atomicAdd(&curp[((unsigned)r) >> 23], 1);
        obuf[p] = r;
    }
    __syncthreads();
    for (int i = t; i < cnt; i += TPB) grec[base + i] = obuf[i];
    int nodeBase = b << LOG_NPB;
    for (int i = t; i < NPB; i += TPB) {
        int node = nodeBase + i;
        if (node < N) dinv[node] = rsqrtf((float)(deg[i] + 1));
    }
}

// ---------------------------------------------------------------------------
// K3: hp = fp8_e4m3( dinv * (x @ W.T) )
__global__ __launch_bounds__(TPB) void k_h(const float* __restrict__ xc,
                                           const float* __restrict__ W,
                                           const float* __restrict__ dinv,
                                           unsigned* __restrict__ hp, int n) {
    __shared__ float sW[256];
    if (threadIdx.x < 256) sW[threadIdx.x] = W[threadIdx.x];
    __syncthreads();
    int i = blockIdx.x * blockDim.x + threadIdx.x;
    int stride = gridDim.x * blockDim.x;
    for (; i < n; i += stride) {
        float x[16];
        const float4* xr = (const float4*)(xc + (size_t)i * 16);
#pragma unroll
        for (int q = 0; q < 4; q++) {
            float4 v = xr[q];
            x[4*q+0] = v.x; x[4*q+1] = v.y; x[4*q+2] = v.z; x[4*q+3] = v.w;
        }
        float di = dinv[i];
        float hv[16];
#pragma unroll
        for (int j = 0; j < 16; j++) {
            float s = 0.f;
#pragma unroll
            for (int k = 0; k < 16; k++) s = fmaf(x[k], sW[j*16 + k], s);
            hv[j] = di * s;
        }
        uint4 w;
        w.x = fp8_pk4(hv[0],  hv[1],  hv[2],  hv[3]);
        w.y = fp8_pk4(hv[4],  hv[5],  hv[6],  hv[7]);
        w.z = fp8_pk4(hv[8],  hv[9],  hv[10], hv[11]);
        w.w = fp8_pk4(hv[12], hv[13], hv[14], hv[15]);
        ((uint4*)hp)[i] = w;
    }
}

// ---------------------------------------------------------------------------
// K_AGG: edge-parallel aggregation + finalize, ONE block per 1024-node
// bucket (489 blocks, all co-resident & in-phase -> L2-resident tile sweep),
// 512 threads (64KB acc -> 2 blocks/CU, 16 waves/CU: doubles LDS/VALU issue
// vs round-2's 8 waves while keeping the same 512-edge chunk window).
// Phase 1: 4 lanes/edge, fp8 decode, s16.16 ds_add_u32 into accI[j][dl^j].
// Phase 2: 16 lanes/row finalize z = relu(dinv*(acc+self)+b); dW/db reduced
// via red[512][17] overlay on accI.
__global__ __launch_bounds__(TPB_A, 4) void k_agg(const int* __restrict__ bcur,
                                                  const int* __restrict__ grec,
                                                  const float* __restrict__ dinv,
                                                  const unsigned* __restrict__ hp32,
                                                  const float* __restrict__ b,
                                                  const float* __restrict__ xc,
                                                  float* __restrict__ z,
                                                  float* __restrict__ partial,
                                                  int nb, int N) {
    __shared__ int accI[16 * NPB];   // 64 KB; red[512][17] (34.8KB) overlays later
    int t = threadIdx.x;
    int bkt = blockIdx.x;
    int cnt = bcur[bkt * 16]; if (cnt > CAP) cnt = CAP;
    const int nodeBase = bkt << LOG_NPB;
    const size_t recBase = (size_t)bkt * CAP;

    {
        int4 zv = make_int4(0, 0, 0, 0);
        int4* a4 = (int4*)accI;
        for (int i = t; i < 16 * NPB / 4; i += TPB_A) a4[i] = zv;
    }
    __syncthreads();

    // ---- Phase 1: edge-parallel scatter (fixed-point int atomics) ----
    int q = t & 3;          // j-quad (j = 4q..4q+3)
    int gi = t >> 2;        // edge slot 0..127
    int j0 = q * 4;
    int base = 0;
    for (; base + 512 <= cnt; base += 512) {
        int rec[4];
#pragma unroll
        for (int u = 0; u < 4; u++) rec[u] = grec[recBase + base + u * 128 + gi];
        unsigned w[4];
#pragma unroll
        for (int u = 0; u < 4; u++)
            w[u] = hp32[(size_t)(((unsigned)rec[u]) >> LOG_NPB) * 4 + q];
#pragma unroll
        for (int u = 0; u < 4; u++) {
            int dl = rec[u] & (NPB - 1);
            float f0, f1, f2, f3;
            fp8_dec4(w[u], f0, f1, f2, f3);
            atomicAdd(&accI[(j0 + 0) * NPB + (dl ^ (j0 + 0))], (int)(f0 * FXS));
            atomicAdd(&accI[(j0 + 1) * NPB + (dl ^ (j0 + 1))], (int)(f1 * FXS));
            atomicAdd(&accI[(j0 + 2) * NPB + (dl ^ (j0 + 2))], (int)(f2 * FXS));
            atomicAdd(&accI[(j0 + 3) * NPB + (dl ^ (j0 + 3))], (int)(f3 * FXS));
        }
    }
    for (int e = base + gi; e < cnt; e += 128) {
        int rec = grec[recBase + e];
        unsigned w = hp32[(size_t)(((unsigned)rec) >> LOG_NPB) * 4 + q];
        int dl = rec & (NPB - 1);
        float f0, f1, f2, f3;
        fp8_dec4(w, f0, f1, f2, f3);
        atomicAdd(&accI[(j0 + 0) * NPB + (dl ^ (j0 + 0))], (int)(f0 * FXS));
        atomicAdd(&accI[(j0 + 1) * NPB + (dl ^ (j0 + 1))], (int)(f1 * FXS));
        atomicAdd(&accI[(j0 + 2) * NPB + (dl ^ (j0 + 2))], (int)(f2 * FXS));
        atomicAdd(&accI[(j0 + 3) * NPB + (dl ^ (j0 + 3))], (int)(f3 * FXS));
    }
    __syncthreads();

    // ---- Phase 2: finalize rows (16 lanes per row, 32 row-groups) ----
    const unsigned char* hpB = (const unsigned char*)hp32;
    int j = t & 15;
    int g0 = t >> 4;        // 0..31 row groups
    float bj = b[j];
    float accW[16];
#pragma unroll
    for (int k = 0; k < 16; k++) accW[k] = 0.f;
    float accB = 0.f;

    for (int i = g0; i < NPB; i += 32) {
        int node = nodeBase + i;
        if (node >= N) break;
        float sv = fp8_dec(hpB[(size_t)node * 16 + j]);           // self-loop
        float aj = fmaf((float)accI[j * NPB + (i ^ j)], FXSI, sv);
        float zj = fmaxf(fmaf(dinv[node], aj, bj), 0.f);
        z[(size_t)node * 16 + j] = zj;
        float wdj = 4.f * zj * zj;
        accB += wdj;
        const float4* xrow = (const float4*)(xc + (size_t)node * 16);
        float4 x0 = xrow[0], x1 = xrow[1], x2 = xrow[2], x3 = xrow[3];
        accW[0]  = fmaf(x0.x, wdj, accW[0]);  accW[1]  = fmaf(x0.y, wdj, accW[1]);
        accW[2]  = fmaf(x0.z, wdj, accW[2]);  accW[3]  = fmaf(x0.w, wdj, accW[3]);
        accW[4]  = fmaf(x1.x, wdj, accW[4]);  accW[5]  = fmaf(x1.y, wdj, accW[5]);
        accW[6]  = fmaf(x1.z, wdj, accW[6]);  accW[7]  = fmaf(x1.w, wdj, accW[7]);
        accW[8]  = fmaf(x2.x, wdj, accW[8]);  accW[9]  = fmaf(x2.y, wdj, accW[9]);
        accW[10] = fmaf(x2.z, wdj, accW[10]); accW[11] = fmaf(x2.w, wdj, accW[11]);
        accW[12] = fmaf(x3.x, wdj, accW[12]); accW[13] = fmaf(x3.y, wdj, accW[13]);
        accW[14] = fmaf(x3.z, wdj, accW[14]); accW[15] = fmaf(x3.w, wdj, accW[15]);
    }
    __syncthreads();   // all accI reads done -> safe to alias red onto accI

    float (*red)[17] = (float (*)[17])accI;   // 512*17*4 = 34816 B <= 64KB
#pragma unroll
    for (int k = 0; k < 16; k++) red[t][k] = accW[k];
    red[t][16] = accB;
    __syncthreads();
    if (t < 256) {
        int kk = t >> 4;
        int jj = t & 15;
        float s = 0.f;
#pragma unroll
        for (int g = 0; g < 32; g++) s += red[g * 16 + jj][kk];
        partial[(size_t)(kk * 16 + jj) * nb + bkt] = s;
    }
    if (t < 16) {
        float sb = 0.f;
#pragma unroll
        for (int g = 0; g < 32; g++) sb += red[g * 16 + t][16];
        partial[(size_t)(256 + t) * nb + bkt] = sb;
    }
}

// K5b: one 64-lane wave per (layer,elem): coalesced sum over nb partials.
__global__ __launch_bounds__(TPB) void k_reduce(const float* __restrict__ partial,
                                                float* __restrict__ acc,
                                                int nb, int total) {
    int wid = (blockIdx.x * blockDim.x + threadIdx.x) >> 6;
    int lane = threadIdx.x & 63;
    if (wid >= total) return;
    const float* p = partial + (size_t)wid * nb;
    float s = 0.f;
    for (int b = lane; b < nb; b += 64) s += p[b];
#pragma unroll
    for (int off = 32; off > 0; off >>= 1) s += __shfl_down(s, off, 64);
    if (lane == 0) acc[wid] = s;
}

// ---------------------------------------------------------------------------
__device__ __forceinline__ float local_loss_f(float g, int positive) {
    const float t = 0.0f;
    if (positive) {
        if (g > t + 10.f) return 0.f;
        if (g < t - 10.f) return t - g;
        return log1pf(expf(t - g));
    } else {
        if (g > t + 10.f) return t + g;
        if (g < t - 10.f) return 0.f;
        return log1pf(expf(g + t));
    }
}

__global__ void k_final(const float* __restrict__ W1, const float* __restrict__ b1,
                        const float* __restrict__ acc, const int* __restrict__ positive,
                        float* __restrict__ outv) {
    int t = threadIdx.x;
    if (t < 256) {
        int jj = t >> 4, kk = t & 15;   // Wc[jj][kk] -= LR * dW[kk][jj]
        float s = 0.f;
#pragma unroll
        for (int l = 0; l < 3; l++) s += acc[l * 272 + kk * 16 + jj];
        outv[1 + t] = W1[t] - LRATE * s;
    }
    if (t < 16) {
        float s = 0.f;
#pragma unroll
        for (int l = 0; l < 3; l++) s += acc[l * 272 + 256 + t];
        outv[257 + t] = b1[t] - LRATE * s;
    }
    if (t == 0) {
        int pos = positive[0];
        float agg = 0.f;
#pragma unroll
        for (int l = 0; l < 3; l++) {
            float g = 0.f;
#pragma unroll
            for (int jj = 0; jj < 16; jj++) g += acc[l * 272 + 256 + jj];
            g *= (1.0f / 64.0f);
            agg += local_loss_f(g, pos);
        }
        outv[0] = agg;
    }
}

extern "C" void kernel_launch(void* const* d_in, const int* in_sizes, int n_in,
                              void* d_out, int out_size, void* d_ws, size_t ws_size,
                              hipStream_t stream) {
    const float* x  = (const float*)d_in[0];
    const int*   ei = (const int*)d_in[1];
    const float* W1 = (const float*)d_in[2];
    const float* b1 = (const float*)d_in[3];
    const float* W2 = (const float*)d_in[4];
    const float* b2 = (const float*)d_in[5];
    const float* W3 = (const float*)d_in[6];
    const float* b3 = (const float*)d_in[7];
    const int* positive = (const int*)d_in[8];
    float* outv = (float*)d_out;

    const int N = in_sizes[0] / 16;
    const int E = in_sizes[1] / 2;
    const int nbuck = (N + NPB - 1) >> LOG_NPB;     // 489 for N=500k

    // Workspace carve-out (256B aligned).
    char* ws = (char*)d_ws;
    size_t off = 0;
    auto carve = [&](size_t bytes) -> void* {
        void* p = ws + off;
        off = (off + bytes + 255) & ~(size_t)255;
        return p;
    };
    int*   bcur   = (int*)  carve((size_t)nbuck * 16 * 4);     // padded cursors
    int*   grec   = (int*)  carve((size_t)nbuck * CAP * 4);    // 28 MB, lives all layers
    float* dinv   = (float*)carve((size_t)N * 4);
    float* acc    = (float*)carve(3 * 272 * 4);
    float* part   = (float*)carve((size_t)3 * 272 * nbuck * 4);
    unsigned* hp  = (unsigned*)carve((size_t)N * 16);          // fp8 rows, 8 MB
    float* P1     = (float*)carve((size_t)N * 64);
    float* P2     = (float*)carve((size_t)N * 64);

    hipMemsetAsync(bcur, 0, (size_t)nbuck * 16 * 4, stream);

    const int* src = ei;
    const int* dst = ei + E;

    // --- Bucketed edge partition + src-tile sort (once, reused 3x) ---
    int partBlocks = (E + CHUNK - 1) / CHUNK;
    k_partition<<<partBlocks, TPB_P, 0, stream>>>(src, dst, bcur, grec, E, nbuck);
    k_sort<<<nbuck, TPB, 0, stream>>>(bcur, grec, dinv, N);

    // --- 3 layers ---
    const float* Ws[3] = {W1, W2, W3};
    const float* bss[3] = {b1, b2, b3};
    float* outs[3] = {P1, P2, P1};   // L1: x->P1; L2: P1->P2; L3: P2->P1

    int nodeBlocks = (N + TPB - 1) / TPB;

    const float* xc = x;
    for (int l = 0; l < 3; l++) {
        k_h<<<nodeBlocks, TPB, 0, stream>>>(xc, Ws[l], dinv, hp, N);
        k_agg<<<nbuck, TPB_A, 0, stream>>>(bcur, grec, dinv, hp, bss[l],
                                           xc, outs[l],
                                           part + (size_t)l * 272 * nbuck, nbuck, N);
        xc = outs[l];
    }
    int totalElems = 3 * 272;
    k_reduce<<<(totalElems * 64 + TPB - 1) / TPB, TPB, 0, stream>>>(part, acc, nbuck, totalElems);
    k_final<<<1, 256, 0, stream>>>(W1, b1, acc, positive, outv);
}